// Round 2
// baseline (235.922 us; speedup 1.0000x reference)
//
#include <hip/hip_runtime.h>
#include <hip/hip_bf16.h>
#include <cstdint>
#include <math.h>

// Problem constants
#define SEQ 1024
#define DIM 2560
#define HD 128
#define NH 20
#define NKV 5
#define QKV_OUT 3840
#define GS 128

typedef __bf16 bf16;
typedef __bf16 bf16x4 __attribute__((ext_vector_type(4)));
typedef __bf16 bf16x8 __attribute__((ext_vector_type(8)));
typedef float f32x4 __attribute__((ext_vector_type(4)));

// ---------------------------------------------------------------------------
// 1b) fused pre-pass: blocks [0,SEQ) = activation quant of x;
//     blocks [SEQ, SEQ+16000) = merged weight dequant (both matrices);
//     blocks [SEQ+16000, SEQ+16256) = RoPE cos/sin table (1024 x 64 x 2 f32).
// ---------------------------------------------------------------------------
__global__ __launch_bounds__(256) void fused_pre(
    const float* __restrict__ x, bf16* __restrict__ act, float* __restrict__ rs,
    const float* __restrict__ w1, const float* __restrict__ ws1, bf16* __restrict__ o1,
    const float* __restrict__ w2, const float* __restrict__ ws2, bf16* __restrict__ o2,
    float* __restrict__ rope, long n1_4, long total4) {
  const int tid = threadIdx.x;
  if (blockIdx.x < SEQ) {
    const int row = blockIdx.x;
    const float* xr = x + (size_t)row * DIM;
    float m = 0.f;
    for (int i = tid; i < DIM; i += 256) m = fmaxf(m, fabsf(xr[i]));
    for (int off = 32; off; off >>= 1) m = fmaxf(m, __shfl_xor(m, off));
    __shared__ float red[4];
    __shared__ float s_bc;
    if ((tid & 63) == 0) red[tid >> 6] = m;
    __syncthreads();
    if (tid == 0) {
      float mm = fmaxf(fmaxf(red[0], red[1]), fmaxf(red[2], red[3]));
      mm = fmaxf(mm, 1e-5f);
      s_bc = 127.f / mm;
      rs[row] = mm / 127.f;
    }
    __syncthreads();
    const float s = s_bc;
    bf16* ar = act + (size_t)row * DIM;
    for (int i = tid; i < DIM; i += 256) {
      float q = rintf(xr[i] * s);
      q = fminf(fmaxf(q, -128.f), 127.f);
      ar[i] = (bf16)q;
    }
  } else {
    long i = (long)(blockIdx.x - SEQ) * 256 + tid;
    if (i < total4) {
      const float* w; const float* ws; bf16* o; long e;
      if (i < n1_4) { w = w1; ws = ws1; o = o1; e = i * 4; }
      else          { w = w2; ws = ws2; o = o2; e = (i - n1_4) * 4; }
      int row = (int)(e / DIM);
      int k = (int)(e % DIM);
      float sc = ws[(size_t)row * (DIM / GS) + (k / GS)];
      float4 wv = *(const float4*)(w + e);
      bf16x4 ov;
      ov[0] = (bf16)(wv.x * sc);
      ov[1] = (bf16)(wv.y * sc);
      ov[2] = (bf16)(wv.z * sc);
      ov[3] = (bf16)(wv.w * sc);
      *(bf16x4*)(o + e) = ov;
    } else {
      long u = i - total4;                 // [0, 65536): (t, freq) pairs
      if (u >= (long)SEQ * 64) return;
      int t = (int)(u >> 6), fi = (int)(u & 63);
      float inv_freq = powf(500000.f, -(float)(2 * fi) * (1.f / 128.f));
      float ang = (float)t * inv_freq;
      float sn, cs;
      sincosf(ang, &sn, &cs);
      rope[u * 2] = cs;
      rope[u * 2 + 1] = sn;
    }
  }
}

// ---------------------------------------------------------------------------
// 3) bf16 MFMA GEMM, single-barrier double-buffered pipeline, XOR swizzle.
//    1-D grid decode: m = b/ND (W sharers spaced ND); nz = b%ND; n = nz%NN;
//    z = nz/NN (split-K).
// ---------------------------------------------------------------------------
__device__ __forceinline__ void gload_lds16(const bf16* g, bf16* l) {
  __builtin_amdgcn_global_load_lds(
      (const __attribute__((address_space(1))) void*)g,
      (__attribute__((address_space(3))) void*)l, 16, 0, 0);
}

template <int BM, int BN>
__global__ __launch_bounds__(256) void gemm_pipe(
    const bf16* __restrict__ A, const bf16* __restrict__ B,
    const float* __restrict__ rs, float* __restrict__ C,
    int N, int K, int Kh, size_t part_stride, int ND, int NN) {
  constexpr int MI = BM / 32;
  constexpr int NW = BN / 32;
  constexpr int APASS = BM / 32;
  constexpr int BPASS = BN / 32;
  __shared__ bf16 As[2][BM * 64];
  __shared__ bf16 Bs[2][BN * 64];
  const int b = (int)blockIdx.x;
  const int mtile = b / ND;
  const int nz = b % ND;
  const int ntile = nz % NN;
  const int z = nz / NN;
  const int tid = threadIdx.x;
  const int w = tid >> 6, l = tid & 63;
  const int row0 = mtile * BM;
  const int col0 = ntile * BN;
  const int wm = (w >> 1) * (BM / 2), wn = (w & 1) * (BN / 2);
  const int lcol = l & 15, quad = l >> 4;
  const int sr = l >> 3, sg = l & 7;
  const bf16* Ag = A + (size_t)row0 * K + (size_t)z * Kh;
  const bf16* Bg = B + (size_t)col0 * K + (size_t)z * Kh;

  f32x4 acc[MI][NW] = {};

#define STAGE_AB(buf, k0)                                                      \
  {                                                                            \
    _Pragma("unroll") for (int i = 0; i < APASS; ++i) {                        \
      int rb = w * (BM / 4) + i * 8;                                           \
      int r = rb + sr;                                                         \
      gload_lds16(Ag + (size_t)r * K + (k0) + ((sg ^ (r & 7)) * 8),            \
                  &As[buf][rb * 64]);                                          \
    }                                                                          \
    _Pragma("unroll") for (int i = 0; i < BPASS; ++i) {                        \
      int rb = w * (BN / 4) + i * 8;                                           \
      int r = rb + sr;                                                         \
      gload_lds16(Bg + (size_t)r * K + (k0) + ((sg ^ (r & 7)) * 8),            \
                  &Bs[buf][rb * 64]);                                          \
    }                                                                          \
  }

  STAGE_AB(0, 0)
  __syncthreads();

  int buf = 0;
  for (int k0 = 0; k0 < Kh; k0 += 64) {
    if (k0 + 64 < Kh) STAGE_AB(buf ^ 1, k0 + 64)
#pragma unroll
    for (int ks = 0; ks < 2; ++ks) {
      bf16x8 af[MI], bff[NW];
#pragma unroll
      for (int mi = 0; mi < MI; ++mi) {
        int R = wm + mi * 16 + lcol;
        af[mi] = *(const bf16x8*)(&As[buf][R * 64 + (((ks * 4 + quad) ^ (R & 7)) * 8)]);
      }
#pragma unroll
      for (int ni = 0; ni < NW; ++ni) {
        int R = wn + ni * 16 + lcol;
        bff[ni] = *(const bf16x8*)(&Bs[buf][R * 64 + (((ks * 4 + quad) ^ (R & 7)) * 8)]);
      }
#pragma unroll
      for (int mi = 0; mi < MI; ++mi)
#pragma unroll
        for (int ni = 0; ni < NW; ++ni)
          acc[mi][ni] = __builtin_amdgcn_mfma_f32_16x16x32_bf16(
              af[mi], bff[ni], acc[mi][ni], 0, 0, 0);
    }
    __syncthreads();
    buf ^= 1;
  }
#undef STAGE_AB

  float* Cp = C + (size_t)z * part_stride;
#pragma unroll
  for (int mi = 0; mi < MI; ++mi) {
#pragma unroll
    for (int ni = 0; ni < NW; ++ni) {
      int col = col0 + wn + ni * 16 + lcol;
#pragma unroll
      for (int r = 0; r < 4; ++r) {
        int row = row0 + wm + mi * 16 + quad * 4 + r;
        Cp[(size_t)row * N + col] = acc[mi][ni][r] * rs[row];
      }
    }
  }
}

// ---------------------------------------------------------------------------
// 3c) split-K x4 reduce for GEMM2: out = sum of 4 partials.
// ---------------------------------------------------------------------------
__global__ __launch_bounds__(256) void reduce_k4(
    const float* __restrict__ P, float* __restrict__ out) {
  const size_t i = (size_t)blockIdx.x * 256 + threadIdx.x;
  const size_t cs4 = (size_t)SEQ * DIM / 4;
  const f32x4* p = (const f32x4*)P;
  f32x4 v = p[i];
  f32x4 a = p[i + cs4];
  f32x4 b = p[i + 2 * cs4];
  f32x4 d = p[i + 3 * cs4];
#pragma unroll
  for (int j = 0; j < 4; ++j) v[j] = v[j] + a[j] + b[j] + d[j];
  *((f32x4*)out + i) = v;
}

// ---------------------------------------------------------------------------
// 4) fused post-pass: blocks [0,6400) = qk rmsnorm+rope (4 wave-units each);
//    blocks [6400, 6480) = V transpose (sum partials -> Vt bf16 [g][d][t]).
//    RoPE angles come from the precomputed table (no per-lane trig).
// ---------------------------------------------------------------------------
__global__ __launch_bounds__(256) void fused_post(
    const float* __restrict__ qkvA, const float* __restrict__ qkvB,
    const float* __restrict__ qw, const float* __restrict__ kw,
    const float* __restrict__ rope,
    bf16* __restrict__ Qo, bf16* __restrict__ Ko, bf16* __restrict__ Vt) {
  __shared__ bf16 Ls[64 * 137];
  const int bx = (int)blockIdx.x;
  const int tid = threadIdx.x;
  if (bx < 6400) {
    const int wave = tid >> 6, i = tid & 63;
    const int u = bx * 4 + wave;           // 0..25599
    const int t = u & 1023, h = u >> 10;   // h in 0..24
    const size_t off = (h < NH)
        ? (size_t)t * QKV_OUT + h * HD
        : (size_t)t * QKV_OUT + 2560 + (h - NH) * HD;
    const float* s1 = qkvA + off;
    const float* s2 = qkvB + off;
    float2 xa = *(const float2*)(s1 + 2 * i);
    float2 xb = *(const float2*)(s2 + 2 * i);
    float x0 = xa.x + xb.x;
    float x1 = xa.y + xb.y;
    float ss = x0 * x0 + x1 * x1;
    for (int off2 = 1; off2 < 64; off2 <<= 1) ss += __shfl_xor(ss, off2);
    float r = rsqrtf(ss * (1.f / 128.f) + 1e-5f);
    const float* wv = (h < NH) ? qw : kw;
    float y0 = x0 * r * wv[2 * i];
    float y1 = x1 * r * wv[2 * i + 1];
    float2 csn = *(const float2*)(rope + ((size_t)t * 64 + i) * 2);
    float cs = csn.x, sn = csn.y;
    float o0 = y0 * cs - y1 * sn;
    float o1 = y0 * sn + y1 * cs;
    if (h < NH) {
      bf16* dst = Qo + ((size_t)t * NH + h) * HD + 2 * i;
      dst[0] = (bf16)o0; dst[1] = (bf16)o1;
    } else {
      bf16* dst = Ko + ((size_t)(h - NH) * SEQ + t) * HD + 2 * i;
      dst[0] = (bf16)o0; dst[1] = (bf16)o1;
    }
  } else {
    const int b2 = bx - 6400;
    const int t0 = (b2 & 15) * 64, g = b2 >> 4;
    {
      const int tl = tid >> 4;
      const int d0 = (tid & 15) * 8;
#pragma unroll
      for (int pass = 0; pass < 4; ++pass) {
        int t = pass * 16 + tl;
        size_t off = (size_t)(t0 + t) * QKV_OUT + 3200 + g * HD + d0;
        float4 a = *(const float4*)(qkvA + off);
        float4 b = *(const float4*)(qkvA + off + 4);
        float4 a2 = *(const float4*)(qkvB + off);
        float4 b2v = *(const float4*)(qkvB + off + 4);
        bf16* dst = Ls + t * 137 + d0;
        dst[0] = (bf16)(a.x + a2.x); dst[1] = (bf16)(a.y + a2.y);
        dst[2] = (bf16)(a.z + a2.z); dst[3] = (bf16)(a.w + a2.w);
        dst[4] = (bf16)(b.x + b2v.x); dst[5] = (bf16)(b.y + b2v.y);
        dst[6] = (bf16)(b.z + b2v.z); dst[7] = (bf16)(b.w + b2v.w);
      }
    }
    __syncthreads();
    {
      const int dl = tid >> 3;
      const int tl0 = (tid & 7) * 8;
#pragma unroll
      for (int pass = 0; pass < 4; ++pass) {
        int d = pass * 32 + dl;
        bf16x8 v;
#pragma unroll
        for (int j = 0; j < 8; ++j) v[j] = Ls[(tl0 + j) * 137 + d];
        *(bf16x8*)(Vt + ((size_t)g * HD + d) * SEQ + t0 + tl0) = v;
      }
    }
  }
}

// ---------------------------------------------------------------------------
// 5) MFMA GQA causal flash attention, split-key (flash-decoding style).
//    Chunks of 4 k-tiles (256 keys): nc(qb) = (qb>>3)+1 in {1..4}.
//    Grid (80, 10): 80 (qb, c) pairs per head-pair column, long-work first:
//      p in [0,32)  -> qb = 31 - p/4, c = p%4   (4 chunks: qb 24..31)
//      p in [32,56) -> qb = 23 - (p-32)/3, c = (p-32)%3
//      p in [56,72) -> qb = 15 - (p-56)/2, c = (p-56)%2
//      p in [72,80) -> qb = 79 - p, c = 0
//    800 blocks x 4 waves = 3200 waves (~3.1/SIMD), critical path 4 tiles.
//    Blocks write UNNORMALIZED f32 O partials + (m, l); merge_quant combines.
// ---------------------------------------------------------------------------
__global__ __launch_bounds__(256, 1) void attn_mfma(
    const bf16* __restrict__ Qb, const bf16* __restrict__ Kb,
    const bf16* __restrict__ Vt, float* __restrict__ Op,
    float* __restrict__ ml) {
  const int p = (int)blockIdx.x;
  int qb, c;
  if (p < 32)      { qb = 31 - (p >> 2);            c = p & 3; }
  else if (p < 56) { int r = p - 32; qb = 23 - r / 3; c = r % 3; }
  else if (p < 72) { int r = p - 56; qb = 15 - (r >> 1); c = r & 1; }
  else             { qb = 79 - p;                   c = 0; }
  const int hp = blockIdx.y;
  const int tid = threadIdx.x;
  const int wave = tid >> 6, lane = tid & 63;
  const int H = (hp >> 1) * 4 + (hp & 1) * 2 + (wave >> 1);
  const int g = H >> 2;
  const int qcol = lane & 15, quad = lane >> 4;
  const int q_tok = qb * 32 + (wave & 1) * 16 + qcol;
  const float scale = 0.08838834764831843f;

  __shared__ bf16 Ks[2][64 * 128];
  __shared__ bf16 Vs[2][128 * 64];

  const bf16* kbase = Kb + (size_t)g * SEQ * HD;
  const bf16* vbase = Vt + (size_t)g * HD * SEQ;

  bf16x8 qf[4];
  {
    const bf16* qp = Qb + ((size_t)q_tok * NH + H) * HD + quad * 8;
#pragma unroll
    for (int kc = 0; kc < 4; ++kc) qf[kc] = *(const bf16x8*)(qp + kc * 32);
  }

  float m_i = -1e30f, l_i = 0.f;
  f32x4 o_acc[8] = {};
  const int kt0 = c * 4;                       // even -> initial buffer parity 0
  int kt_max = kt0 + 3;
  {
    int ktg = qb >> 1;
    if (ktg < kt_max) kt_max = ktg;
  }

  const int k_r = lane >> 4, k_g = lane & 15;
  const int v_r = lane >> 3, v_g = lane & 7;

#define STAGE(buf, key0)                                                       \
  {                                                                            \
    _Pragma("unroll") for (int p2 = 0; p2 < 4; ++p2) {                         \
      int r0 = wave * 16 + p2 * 4;                                             \
      int r = r0 + k_r;                                                        \
      gload_lds16(kbase + (size_t)((key0) + r) * HD + ((k_g ^ (r & 15)) * 8),  \
                  &Ks[buf][r0 * 128]);                                         \
    }                                                                          \
    _Pragma("unroll") for (int p2 = 0; p2 < 4; ++p2) {                         \
      int r0 = wave * 32 + p2 * 8;                                             \
      int r = r0 + v_r;                                                        \
      gload_lds16(vbase + (size_t)r * SEQ + (key0) + ((v_g ^ (r & 7)) * 8),    \
                  &Vs[buf][r0 * 64]);                                          \
    }                                                                          \
  }

  STAGE(0, kt0 * 64)

  for (int kt = kt0; kt <= kt_max; ++kt) {
    const int key0 = kt * 64;
    __syncthreads();
    if (kt < kt_max) STAGE((kt + 1) & 1, key0 + 64)
    const bf16* Kt = Ks[kt & 1];
    const bf16* Vtile = Vs[kt & 1];

    // ---- batched K fragment loads (16 ds_read_b128, no dependent use) ----
    bf16x8 kf[4][4];
#pragma unroll
    for (int mg = 0; mg < 4; ++mg) {
      const int R = mg * 16 + qcol;
      const bf16* krow = Kt + R * 128;
#pragma unroll
      for (int kc = 0; kc < 4; ++kc)
        kf[mg][kc] = *(const bf16x8*)(krow + (((kc * 4 + quad) ^ (R & 15)) * 8));
    }
    // ---- S^T = K · Q^T ----
    f32x4 s[4];
#pragma unroll
    for (int mg = 0; mg < 4; ++mg) {
      f32x4 acc = {0.f, 0.f, 0.f, 0.f};
#pragma unroll
      for (int kc = 0; kc < 4; ++kc)
        acc = __builtin_amdgcn_mfma_f32_16x16x32_bf16(kf[mg][kc], qf[kc], acc, 0, 0, 0);
      s[mg] = acc;
    }

    // ---- batched V fragment loads (32 ds_read_b64; overlap with softmax) --
    bf16x8 vf[8][2];
#pragma unroll
    for (int mg2 = 0; mg2 < 8; ++mg2) {
      const int R = mg2 * 16 + qcol;
      const bf16* vrow = Vtile + R * 64;
#pragma unroll
      for (int cc = 0; cc < 2; ++cc) {
        int g8a = cc * 8 + quad;
        int g8b = cc * 8 + 4 + quad;
        bf16x4 v0 = *(const bf16x4*)(vrow + ((g8a >> 1) ^ (R & 7)) * 8 + (g8a & 1) * 4);
        bf16x4 v1 = *(const bf16x4*)(vrow + ((g8b >> 1) ^ (R & 7)) * 8 + (g8b & 1) * 4);
#pragma unroll
        for (int j = 0; j < 4; ++j) { vf[mg2][cc][j] = v0[j]; vf[mg2][cc][j + 4] = v1[j]; }
      }
    }

    // ---- scale + causal mask + online softmax ----
    float mt = -1e30f;
#pragma unroll
    for (int mg = 0; mg < 4; ++mg)
#pragma unroll
      for (int r = 0; r < 4; ++r) {
        int key = key0 + mg * 16 + quad * 4 + r;
        float v = (key <= q_tok) ? s[mg][r] * scale : -1e30f;
        s[mg][r] = v;
        mt = fmaxf(mt, v);
      }
    mt = fmaxf(mt, __shfl_xor(mt, 16));
    mt = fmaxf(mt, __shfl_xor(mt, 32));
    float mnew = fmaxf(m_i, mt);
    float alpha = __expf(m_i - mnew);
    float ps = 0.f;
#pragma unroll
    for (int mg = 0; mg < 4; ++mg)
#pragma unroll
      for (int r = 0; r < 4; ++r) {
        float pv = __expf(s[mg][r] - mnew);
        s[mg][r] = pv;
        ps += pv;
      }
    ps += __shfl_xor(ps, 16);
    ps += __shfl_xor(ps, 32);
    l_i = l_i * alpha + ps;
    m_i = mnew;
#pragma unroll
    for (int mg2 = 0; mg2 < 8; ++mg2)
#pragma unroll
      for (int r = 0; r < 4; ++r) o_acc[mg2][r] *= alpha;

    // ---- P^T B-frags from own regs (key = mg*16 + quad*4 + r) ----
    bf16x8 pb[2];
#pragma unroll
    for (int cc = 0; cc < 2; ++cc)
#pragma unroll
      for (int j = 0; j < 8; ++j)
        pb[cc][j] = (bf16)s[cc * 2 + (j >> 2)][j & 3];

    // ---- O^T += V^T · P^T ----
#pragma unroll
    for (int mg2 = 0; mg2 < 8; ++mg2) {
      f32x4 acc = o_acc[mg2];
#pragma unroll
      for (int cc = 0; cc < 2; ++cc)
        acc = __builtin_amdgcn_mfma_f32_16x16x32_bf16(vf[mg2][cc], pb[cc], acc, 0, 0, 0);
      o_acc[mg2] = acc;
    }
  }
#undef STAGE

  // ---- write UNNORMALIZED partial O (f32) + per-(token,head) m,l ----
  float* op = Op + ((size_t)c * SEQ + q_tok) * DIM + (size_t)H * HD + quad * 4;
#pragma unroll
  for (int mg2 = 0; mg2 < 8; ++mg2)
    *(f32x4*)(op + mg2 * 16) = o_acc[mg2];
  if (lane < 16) {
    size_t mloff = (((size_t)c * SEQ + q_tok) * NH + H) * 2;
    ml[mloff] = m_i;
    ml[mloff + 1] = l_i;
  }
}

// ---------------------------------------------------------------------------
// 6) merge (<=4 split-key partials per (token, head)) + per-token int8 quant.
//    One block per token. Partial layout: Op[c][t][2560] f32, chunk stride
//    SEQ*DIM; ml[c][t][h][2] f32. nc(t) = (t>>8)+1 in {1..4}.
// ---------------------------------------------------------------------------
__global__ __launch_bounds__(256) void merge_quant(
    const float* __restrict__ Op, const float* __restrict__ ml,
    bf16* __restrict__ act, float* __restrict__ rs) {
  const int t = blockIdx.x;
  const int tid = threadIdx.x;
  const int nc = (t >> 8) + 1;                // chunks covering this token: 1..4
  __shared__ float sw[4][NH];
  __shared__ float red[4];
  __shared__ float s_bc;
  if (tid < NH) {
    const size_t base = ((size_t)t * NH + tid) * 2;
    const size_t cs = (size_t)SEQ * NH * 2;
    float m[4], l[4];
    float M = -1e30f;
#pragma unroll
    for (int cc = 0; cc < 4; ++cc) {
      if (cc < nc) {
        m[cc] = ml[base + cc * cs];
        l[cc] = ml[base + cc * cs + 1];
        M = fmaxf(M, m[cc]);
      }
    }
    float w[4];
    float L = 0.f;
#pragma unroll
    for (int cc = 0; cc < 4; ++cc) {
      if (cc < nc) { w[cc] = __expf(m[cc] - M); L += w[cc] * l[cc]; }
      else w[cc] = 0.f;
    }
    const float invL = 1.f / L;
#pragma unroll
    for (int cc = 0; cc < 4; ++cc) sw[cc][tid] = w[cc] * invL;
  }
  __syncthreads();
  float vals[10];
  float amax = 0.f;
  const float* ob = Op + (size_t)t * DIM;
  const size_t cs = (size_t)SEQ * DIM;
#pragma unroll
  for (int j = 0; j < 10; ++j) {
    int d = j * 256 + tid;
    int h = d >> 7;
    float v = ob[d] * sw[0][h];
    if (nc > 1) v += ob[d + cs] * sw[1][h];
    if (nc > 2) v += ob[d + 2 * cs] * sw[2][h];
    if (nc > 3) v += ob[d + 3 * cs] * sw[3][h];
    vals[j] = v;
    amax = fmaxf(amax, fabsf(v));
  }
  for (int off = 32; off; off >>= 1) amax = fmaxf(amax, __shfl_xor(amax, off));
  if ((tid & 63) == 0) red[tid >> 6] = amax;
  __syncthreads();
  if (tid == 0) {
    float mm = fmaxf(fmaxf(red[0], red[1]), fmaxf(red[2], red[3]));
    mm = fmaxf(mm, 1e-5f);
    s_bc = 127.f / mm;
    rs[t] = mm / 127.f;
  }
  __syncthreads();
  const float s = s_bc;
  bf16* ar = act + (size_t)t * DIM;
#pragma unroll
  for (int j = 0; j < 10; ++j) {
    float q = rintf(vals[j] * s);
    q = fminf(fmaxf(q, -128.f), 127.f);
    ar[j * 256 + tid] = (bf16)q;
  }
}

// ---------------------------------------------------------------------------
extern "C" void kernel_launch(void* const* d_in, const int* in_sizes, int n_in,
                              void* d_out, int out_size, void* d_ws, size_t ws_size,
                              hipStream_t stream) {
  const float* x      = (const float*)d_in[0];
  const float* w_qkv  = (const float*)d_in[1];
  const float* ws_qkv = (const float*)d_in[2];
  const float* w_o    = (const float*)d_in[3];
  const float* ws_o   = (const float*)d_in[4];
  const float* qnw    = (const float*)d_in[5];
  const float* knw    = (const float*)d_in[6];
  float* out = (float*)d_out;

  // Workspace is 256 MiB (fill evidence); ~168 MB used, no aliasing needed.
  char* p = (char*)d_ws;
  bf16*  act1 = (bf16*)p;  p += (size_t)SEQ * DIM * 2;
  float* rs1  = (float*)p; p += 4096;
  bf16*  wqdq = (bf16*)p;  p += (size_t)QKV_OUT * DIM * 2;
  bf16*  wodq = (bf16*)p;  p += (size_t)DIM * DIM * 2;
  float* qkvA = (float*)p; p += (size_t)SEQ * QKV_OUT * 4;
  float* qkvB = (float*)p; p += (size_t)SEQ * QKV_OUT * 4;
  bf16*  Qb   = (bf16*)p;  p += (size_t)SEQ * NH * HD * 2;
  bf16*  Kb   = (bf16*)p;  p += (size_t)NKV * SEQ * HD * 2;
  bf16*  Vt   = (bf16*)p;  p += (size_t)NKV * HD * SEQ * 2;
  bf16*  act2 = (bf16*)p;  p += (size_t)SEQ * DIM * 2;
  float* rs2  = (float*)p; p += 4096;
  float* rope = (float*)p; p += (size_t)SEQ * 64 * 2 * 4;       // 512 KB
  float* Opart = (float*)p; p += (size_t)4 * SEQ * DIM * 4;     // 41.9 MB
  float* mlbuf = (float*)p; p += (size_t)4 * SEQ * NH * 2 * 4;  // 655 KB
  float* g2part = (float*)p; p += (size_t)4 * SEQ * DIM * 4;    // 41.9 MB

  {
    long n1_4 = (long)QKV_OUT * DIM / 4;                 // 2,457,600
    long total4 = n1_4 + (long)DIM * DIM / 4;            // 4,096,000 (= 16000*256)
    int dq_blocks = (int)((total4 + 255) / 256);         // 16000
    int rope_blocks = (SEQ * 64 + 255) / 256;            // 256
    fused_pre<<<SEQ + dq_blocks + rope_blocks, 256, 0, stream>>>(
        x, act1, rs1, w_qkv, ws_qkv, wqdq, w_o, ws_o, wodq, rope, n1_4, total4);
  }
  // GEMM1: BM=128, BN=128, split-K x2. Grid 480 1-D: m = b/60, n = (b%60)%30,
  // z = (b%60)/30.
  gemm_pipe<128, 128><<<480, 256, 0, stream>>>(
      act1, wqdq, rs1, qkvA, QKV_OUT, DIM, DIM / 2, (size_t)SEQ * QKV_OUT, 60, 30);
  // fused qk rmsnorm+rope (6400 blocks) + V transpose (80 blocks)
  fused_post<<<6480, 256, 0, stream>>>(qkvA, qkvB, qnw, knw, rope, Qb, Kb, Vt);
  // split-key attention: 80 (qb, chunk) pairs x 10 head-pair columns
  attn_mfma<<<dim3(80, 10), 256, 0, stream>>>(Qb, Kb, Vt, Opart, mlbuf);
  // merge partials + per-token quant
  merge_quant<<<SEQ, 256, 0, stream>>>(Opart, mlbuf, act2, rs2);
  // GEMM2: BM=128, BN=128, split-K x4. Grid 640 1-D: m = b/80, n = (b%80)%20,
  // z = (b%80)/20. Kh = 640.
  gemm_pipe<128, 128><<<640, 256, 0, stream>>>(
      act2, wodq, rs2, g2part, DIM, DIM, DIM / 4, (size_t)SEQ * DIM, 80, 20);
  // sum the 4 split-K partials into the final output
  reduce_k4<<<SEQ * DIM / 1024, 256, 0, stream>>>(g2part, out);
}

// Round 3
// 217.052 us; speedup vs baseline: 1.0869x; 1.0869x over previous
//
#include <hip/hip_runtime.h>
#include <hip/hip_bf16.h>
#include <cstdint>
#include <math.h>

// Problem constants
#define SEQ 1024
#define DIM 2560
#define HD 128
#define NH 20
#define NKV 5
#define QKV_OUT 3840
#define GS 128

typedef __bf16 bf16;
typedef __bf16 bf16x4 __attribute__((ext_vector_type(4)));
typedef __bf16 bf16x8 __attribute__((ext_vector_type(8)));
typedef float f32x4 __attribute__((ext_vector_type(4)));

// ---------------------------------------------------------------------------
// 1b) fused pre-pass: blocks [0,SEQ) = activation quant of x;
//     blocks [SEQ, SEQ+9600) = w_qkv dequant;
//     blocks [SEQ+9600, SEQ+9856) = RoPE cos/sin table (1024 x 64 x 2 f32).
//     (w_o dequant moved into the attn launch - it overlaps attn's idle BW.)
// ---------------------------------------------------------------------------
__global__ __launch_bounds__(256) void fused_pre(
    const float* __restrict__ x, bf16* __restrict__ act, float* __restrict__ rs,
    const float* __restrict__ w1, const float* __restrict__ ws1, bf16* __restrict__ o1,
    float* __restrict__ rope, long n1_4) {
  const int tid = threadIdx.x;
  if (blockIdx.x < SEQ) {
    const int row = blockIdx.x;
    const float* xr = x + (size_t)row * DIM;
    float m = 0.f;
    for (int i = tid; i < DIM; i += 256) m = fmaxf(m, fabsf(xr[i]));
    for (int off = 32; off; off >>= 1) m = fmaxf(m, __shfl_xor(m, off));
    __shared__ float red[4];
    __shared__ float s_bc;
    if ((tid & 63) == 0) red[tid >> 6] = m;
    __syncthreads();
    if (tid == 0) {
      float mm = fmaxf(fmaxf(red[0], red[1]), fmaxf(red[2], red[3]));
      mm = fmaxf(mm, 1e-5f);
      s_bc = 127.f / mm;
      rs[row] = mm / 127.f;
    }
    __syncthreads();
    const float s = s_bc;
    bf16* ar = act + (size_t)row * DIM;
    for (int i = tid; i < DIM; i += 256) {
      float q = rintf(xr[i] * s);
      q = fminf(fmaxf(q, -128.f), 127.f);
      ar[i] = (bf16)q;
    }
  } else {
    long i = (long)(blockIdx.x - SEQ) * 256 + tid;
    if (i < n1_4) {
      long e = i * 4;
      int row = (int)(e / DIM);
      int k = (int)(e % DIM);
      float sc = ws1[(size_t)row * (DIM / GS) + (k / GS)];
      float4 wv = *(const float4*)(w1 + e);
      bf16x4 ov;
      ov[0] = (bf16)(wv.x * sc);
      ov[1] = (bf16)(wv.y * sc);
      ov[2] = (bf16)(wv.z * sc);
      ov[3] = (bf16)(wv.w * sc);
      *(bf16x4*)(o1 + e) = ov;
    } else {
      long u = i - n1_4;                  // [0, 65536): (t, freq) pairs
      if (u >= (long)SEQ * 64) return;
      int t = (int)(u >> 6), fi = (int)(u & 63);
      float inv_freq = powf(500000.f, -(float)(2 * fi) * (1.f / 128.f));
      float ang = (float)t * inv_freq;
      float sn, cs;
      sincosf(ang, &sn, &cs);
      rope[u * 2] = cs;
      rope[u * 2 + 1] = sn;
    }
  }
}

// ---------------------------------------------------------------------------
// 3) bf16 MFMA GEMM, single-barrier double-buffered pipeline, XOR swizzle.
//    1-D grid decode: m = b/ND (W sharers spaced ND); nz = b%ND; n = nz%NN;
//    z = nz/NN (split-K).
// ---------------------------------------------------------------------------
__device__ __forceinline__ void gload_lds16(const bf16* g, bf16* l) {
  __builtin_amdgcn_global_load_lds(
      (const __attribute__((address_space(1))) void*)g,
      (__attribute__((address_space(3))) void*)l, 16, 0, 0);
}

template <int BM, int BN>
__global__ __launch_bounds__(256) void gemm_pipe(
    const bf16* __restrict__ A, const bf16* __restrict__ B,
    const float* __restrict__ rs, float* __restrict__ C,
    int N, int K, int Kh, size_t part_stride, int ND, int NN) {
  constexpr int MI = BM / 32;
  constexpr int NW = BN / 32;
  constexpr int APASS = BM / 32;
  constexpr int BPASS = BN / 32;
  __shared__ bf16 As[2][BM * 64];
  __shared__ bf16 Bs[2][BN * 64];
  const int b = (int)blockIdx.x;
  const int mtile = b / ND;
  const int nz = b % ND;
  const int ntile = nz % NN;
  const int z = nz / NN;
  const int tid = threadIdx.x;
  const int w = tid >> 6, l = tid & 63;
  const int row0 = mtile * BM;
  const int col0 = ntile * BN;
  const int wm = (w >> 1) * (BM / 2), wn = (w & 1) * (BN / 2);
  const int lcol = l & 15, quad = l >> 4;
  const int sr = l >> 3, sg = l & 7;
  const bf16* Ag = A + (size_t)row0 * K + (size_t)z * Kh;
  const bf16* Bg = B + (size_t)col0 * K + (size_t)z * Kh;

  f32x4 acc[MI][NW] = {};

#define STAGE_AB(buf, k0)                                                      \
  {                                                                            \
    _Pragma("unroll") for (int i = 0; i < APASS; ++i) {                        \
      int rb = w * (BM / 4) + i * 8;                                           \
      int r = rb + sr;                                                         \
      gload_lds16(Ag + (size_t)r * K + (k0) + ((sg ^ (r & 7)) * 8),            \
                  &As[buf][rb * 64]);                                          \
    }                                                                          \
    _Pragma("unroll") for (int i = 0; i < BPASS; ++i) {                        \
      int rb = w * (BN / 4) + i * 8;                                           \
      int r = rb + sr;                                                         \
      gload_lds16(Bg + (size_t)r * K + (k0) + ((sg ^ (r & 7)) * 8),            \
                  &Bs[buf][rb * 64]);                                          \
    }                                                                          \
  }

  STAGE_AB(0, 0)
  __syncthreads();

  int buf = 0;
  for (int k0 = 0; k0 < Kh; k0 += 64) {
    if (k0 + 64 < Kh) STAGE_AB(buf ^ 1, k0 + 64)
#pragma unroll
    for (int ks = 0; ks < 2; ++ks) {
      bf16x8 af[MI], bff[NW];
#pragma unroll
      for (int mi = 0; mi < MI; ++mi) {
        int R = wm + mi * 16 + lcol;
        af[mi] = *(const bf16x8*)(&As[buf][R * 64 + (((ks * 4 + quad) ^ (R & 7)) * 8)]);
      }
#pragma unroll
      for (int ni = 0; ni < NW; ++ni) {
        int R = wn + ni * 16 + lcol;
        bff[ni] = *(const bf16x8*)(&Bs[buf][R * 64 + (((ks * 4 + quad) ^ (R & 7)) * 8)]);
      }
#pragma unroll
      for (int mi = 0; mi < MI; ++mi)
#pragma unroll
        for (int ni = 0; ni < NW; ++ni)
          acc[mi][ni] = __builtin_amdgcn_mfma_f32_16x16x32_bf16(
              af[mi], bff[ni], acc[mi][ni], 0, 0, 0);
    }
    __syncthreads();
    buf ^= 1;
  }
#undef STAGE_AB

  float* Cp = C + (size_t)z * part_stride;
#pragma unroll
  for (int mi = 0; mi < MI; ++mi) {
#pragma unroll
    for (int ni = 0; ni < NW; ++ni) {
      int col = col0 + wn + ni * 16 + lcol;
#pragma unroll
      for (int r = 0; r < 4; ++r) {
        int row = row0 + wm + mi * 16 + quad * 4 + r;
        Cp[(size_t)row * N + col] = acc[mi][ni][r] * rs[row];
      }
    }
  }
}

// ---------------------------------------------------------------------------
// 4) fused post-pass: blocks [0,6400) = qk rmsnorm+rope (4 wave-units each);
//    blocks [6400, 6480) = V transpose (sum partials -> Vt bf16 [g][d][t]).
//    RoPE angles come from the precomputed table (no per-lane trig).
// ---------------------------------------------------------------------------
__global__ __launch_bounds__(256) void fused_post(
    const float* __restrict__ qkvA, const float* __restrict__ qkvB,
    const float* __restrict__ qw, const float* __restrict__ kw,
    const float* __restrict__ rope,
    bf16* __restrict__ Qo, bf16* __restrict__ Ko, bf16* __restrict__ Vt) {
  __shared__ bf16 Ls[64 * 137];
  const int bx = (int)blockIdx.x;
  const int tid = threadIdx.x;
  if (bx < 6400) {
    const int wave = tid >> 6, i = tid & 63;
    const int u = bx * 4 + wave;           // 0..25599
    const int t = u & 1023, h = u >> 10;   // h in 0..24
    const size_t off = (h < NH)
        ? (size_t)t * QKV_OUT + h * HD
        : (size_t)t * QKV_OUT + 2560 + (h - NH) * HD;
    const float* s1 = qkvA + off;
    const float* s2 = qkvB + off;
    float2 xa = *(const float2*)(s1 + 2 * i);
    float2 xb = *(const float2*)(s2 + 2 * i);
    float x0 = xa.x + xb.x;
    float x1 = xa.y + xb.y;
    float ss = x0 * x0 + x1 * x1;
    for (int off2 = 1; off2 < 64; off2 <<= 1) ss += __shfl_xor(ss, off2);
    float r = rsqrtf(ss * (1.f / 128.f) + 1e-5f);
    const float* wv = (h < NH) ? qw : kw;
    float y0 = x0 * r * wv[2 * i];
    float y1 = x1 * r * wv[2 * i + 1];
    float2 csn = *(const float2*)(rope + ((size_t)t * 64 + i) * 2);
    float cs = csn.x, sn = csn.y;
    float o0 = y0 * cs - y1 * sn;
    float o1 = y0 * sn + y1 * cs;
    if (h < NH) {
      bf16* dst = Qo + ((size_t)t * NH + h) * HD + 2 * i;
      dst[0] = (bf16)o0; dst[1] = (bf16)o1;
    } else {
      bf16* dst = Ko + ((size_t)(h - NH) * SEQ + t) * HD + 2 * i;
      dst[0] = (bf16)o0; dst[1] = (bf16)o1;
    }
  } else {
    const int b2 = bx - 6400;
    const int t0 = (b2 & 15) * 64, g = b2 >> 4;
    {
      const int tl = tid >> 4;
      const int d0 = (tid & 15) * 8;
#pragma unroll
      for (int pass = 0; pass < 4; ++pass) {
        int t = pass * 16 + tl;
        size_t off = (size_t)(t0 + t) * QKV_OUT + 3200 + g * HD + d0;
        float4 a = *(const float4*)(qkvA + off);
        float4 b = *(const float4*)(qkvA + off + 4);
        float4 a2 = *(const float4*)(qkvB + off);
        float4 b2v = *(const float4*)(qkvB + off + 4);
        bf16* dst = Ls + t * 137 + d0;
        dst[0] = (bf16)(a.x + a2.x); dst[1] = (bf16)(a.y + a2.y);
        dst[2] = (bf16)(a.z + a2.z); dst[3] = (bf16)(a.w + a2.w);
        dst[4] = (bf16)(b.x + b2v.x); dst[5] = (bf16)(b.y + b2v.y);
        dst[6] = (bf16)(b.z + b2v.z); dst[7] = (bf16)(b.w + b2v.w);
      }
    }
    __syncthreads();
    {
      const int dl = tid >> 3;
      const int tl0 = (tid & 7) * 8;
#pragma unroll
      for (int pass = 0; pass < 4; ++pass) {
        int d = pass * 32 + dl;
        bf16x8 v;
#pragma unroll
        for (int j = 0; j < 8; ++j) v[j] = Ls[(tl0 + j) * 137 + d];
        *(bf16x8*)(Vt + ((size_t)g * HD + d) * SEQ + t0 + tl0) = v;
      }
    }
  }
}

// ---------------------------------------------------------------------------
// 5) MFMA GQA causal flash attention, split-key (round-1 6-tile chunks),
//    PLUS w_o dequant plane: blocks [600, 2200) dequantize w_o -> wodq
//    (pure memory work overlapping attn's idle BW; wodq consumed by GEMM2).
//    attn decode (b < 600): p = b%60, hp = b/60.
//      p in [0,24)  -> qb = 31 - p/3, c = p%3   (3 chunks)
//      p in [24,48) -> qb = 23 - (p-24)/2, c = (p-24)%2
//      p in [48,60) -> qb = 59 - p, c = 0
// ---------------------------------------------------------------------------
__global__ __launch_bounds__(256, 1) void attn_mfma(
    const bf16* __restrict__ Qb, const bf16* __restrict__ Kb,
    const bf16* __restrict__ Vt, float* __restrict__ Op,
    float* __restrict__ ml,
    const float* __restrict__ w2, const float* __restrict__ ws2,
    bf16* __restrict__ o2) {
  const int bxi = (int)blockIdx.x;
  const int tid = threadIdx.x;
  if (bxi >= 600) {
    // ---- w_o dequant: 1600 blocks x 1024 float4 each ----
    const long b2 = bxi - 600;
    const long base4 = b2 * 1024 + tid;
#pragma unroll
    for (int it = 0; it < 4; ++it) {
      long e = (base4 + it * 256) * 4;
      int row = (int)(e / DIM);
      int k = (int)(e % DIM);
      float sc = ws2[(size_t)row * (DIM / GS) + (k / GS)];
      float4 wv = *(const float4*)(w2 + e);
      bf16x4 ov;
      ov[0] = (bf16)(wv.x * sc);
      ov[1] = (bf16)(wv.y * sc);
      ov[2] = (bf16)(wv.z * sc);
      ov[3] = (bf16)(wv.w * sc);
      *(bf16x4*)(o2 + e) = ov;
    }
    return;
  }
  const int p = bxi % 60;
  const int hp = bxi / 60;
  int qb, c;
  if (p < 24)      { qb = 31 - p / 3;            c = p % 3; }
  else if (p < 48) { int r = p - 24; qb = 23 - (r >> 1); c = r & 1; }
  else             { qb = 59 - p;                c = 0; }
  const int wave = tid >> 6, lane = tid & 63;
  const int H = (hp >> 1) * 4 + (hp & 1) * 2 + (wave >> 1);
  const int g = H >> 2;
  const int qcol = lane & 15, quad = lane >> 4;
  const int q_tok = qb * 32 + (wave & 1) * 16 + qcol;
  const float scale = 0.08838834764831843f;

  __shared__ bf16 Ks[2][64 * 128];
  __shared__ bf16 Vs[2][128 * 64];

  const bf16* kbase = Kb + (size_t)g * SEQ * HD;
  const bf16* vbase = Vt + (size_t)g * HD * SEQ;

  bf16x8 qf[4];
  {
    const bf16* qp = Qb + ((size_t)q_tok * NH + H) * HD + quad * 8;
#pragma unroll
    for (int kc = 0; kc < 4; ++kc) qf[kc] = *(const bf16x8*)(qp + kc * 32);
  }

  float m_i = -1e30f, l_i = 0.f;
  f32x4 o_acc[8] = {};
  const int kt0 = c * 6;                       // even -> initial buffer parity 0
  int kt_max = kt0 + 5;
  {
    int ktg = (qb * 32 + 31) >> 6;
    if (ktg < kt_max) kt_max = ktg;
  }

  const int k_r = lane >> 4, k_g = lane & 15;
  const int v_r = lane >> 3, v_g = lane & 7;

#define STAGE(buf, key0)                                                       \
  {                                                                            \
    _Pragma("unroll") for (int p2 = 0; p2 < 4; ++p2) {                         \
      int r0 = wave * 16 + p2 * 4;                                             \
      int r = r0 + k_r;                                                        \
      gload_lds16(kbase + (size_t)((key0) + r) * HD + ((k_g ^ (r & 15)) * 8),  \
                  &Ks[buf][r0 * 128]);                                         \
    }                                                                          \
    _Pragma("unroll") for (int p2 = 0; p2 < 4; ++p2) {                         \
      int r0 = wave * 32 + p2 * 8;                                             \
      int r = r0 + v_r;                                                        \
      gload_lds16(vbase + (size_t)r * SEQ + (key0) + ((v_g ^ (r & 7)) * 8),    \
                  &Vs[buf][r0 * 64]);                                          \
    }                                                                          \
  }

  STAGE(0, kt0 * 64)

  for (int kt = kt0; kt <= kt_max; ++kt) {
    const int key0 = kt * 64;
    __syncthreads();
    if (kt < kt_max) STAGE((kt + 1) & 1, key0 + 64)
    const bf16* Kt = Ks[kt & 1];
    const bf16* Vtile = Vs[kt & 1];

    // ---- batched K fragment loads (16 ds_read_b128, no dependent use) ----
    bf16x8 kf[4][4];
#pragma unroll
    for (int mg = 0; mg < 4; ++mg) {
      const int R = mg * 16 + qcol;
      const bf16* krow = Kt + R * 128;
#pragma unroll
      for (int kc = 0; kc < 4; ++kc)
        kf[mg][kc] = *(const bf16x8*)(krow + (((kc * 4 + quad) ^ (R & 15)) * 8));
    }
    // ---- S^T = K · Q^T ----
    f32x4 s[4];
#pragma unroll
    for (int mg = 0; mg < 4; ++mg) {
      f32x4 acc = {0.f, 0.f, 0.f, 0.f};
#pragma unroll
      for (int kc = 0; kc < 4; ++kc)
        acc = __builtin_amdgcn_mfma_f32_16x16x32_bf16(kf[mg][kc], qf[kc], acc, 0, 0, 0);
      s[mg] = acc;
    }

    // ---- batched V fragment loads (32 ds_read_b64; overlap with softmax) --
    bf16x8 vf[8][2];
#pragma unroll
    for (int mg2 = 0; mg2 < 8; ++mg2) {
      const int R = mg2 * 16 + qcol;
      const bf16* vrow = Vtile + R * 64;
#pragma unroll
      for (int cc = 0; cc < 2; ++cc) {
        int g8a = cc * 8 + quad;
        int g8b = cc * 8 + 4 + quad;
        bf16x4 v0 = *(const bf16x4*)(vrow + ((g8a >> 1) ^ (R & 7)) * 8 + (g8a & 1) * 4);
        bf16x4 v1 = *(const bf16x4*)(vrow + ((g8b >> 1) ^ (R & 7)) * 8 + (g8b & 1) * 4);
#pragma unroll
        for (int j = 0; j < 4; ++j) { vf[mg2][cc][j] = v0[j]; vf[mg2][cc][j + 4] = v1[j]; }
      }
    }

    // ---- scale + causal mask + online softmax ----
    float mt = -1e30f;
#pragma unroll
    for (int mg = 0; mg < 4; ++mg)
#pragma unroll
      for (int r = 0; r < 4; ++r) {
        int key = key0 + mg * 16 + quad * 4 + r;
        float v = (key <= q_tok) ? s[mg][r] * scale : -1e30f;
        s[mg][r] = v;
        mt = fmaxf(mt, v);
      }
    mt = fmaxf(mt, __shfl_xor(mt, 16));
    mt = fmaxf(mt, __shfl_xor(mt, 32));
    float mnew = fmaxf(m_i, mt);
    float alpha = __expf(m_i - mnew);
    float ps = 0.f;
#pragma unroll
    for (int mg = 0; mg < 4; ++mg)
#pragma unroll
      for (int r = 0; r < 4; ++r) {
        float pv = __expf(s[mg][r] - mnew);
        s[mg][r] = pv;
        ps += pv;
      }
    ps += __shfl_xor(ps, 16);
    ps += __shfl_xor(ps, 32);
    l_i = l_i * alpha + ps;
    m_i = mnew;
#pragma unroll
    for (int mg2 = 0; mg2 < 8; ++mg2)
#pragma unroll
      for (int r = 0; r < 4; ++r) o_acc[mg2][r] *= alpha;

    // ---- P^T B-frags from own regs (key = mg*16 + quad*4 + r) ----
    bf16x8 pb[2];
#pragma unroll
    for (int cc = 0; cc < 2; ++cc)
#pragma unroll
      for (int j = 0; j < 8; ++j)
        pb[cc][j] = (bf16)s[cc * 2 + (j >> 2)][j & 3];

    // ---- O^T += V^T · P^T ----
#pragma unroll
    for (int mg2 = 0; mg2 < 8; ++mg2) {
      f32x4 acc = o_acc[mg2];
#pragma unroll
      for (int cc = 0; cc < 2; ++cc)
        acc = __builtin_amdgcn_mfma_f32_16x16x32_bf16(vf[mg2][cc], pb[cc], acc, 0, 0, 0);
      o_acc[mg2] = acc;
    }
  }
#undef STAGE

  // ---- write UNNORMALIZED partial O (f32) + per-(token,head) m,l ----
  float* op = Op + ((size_t)c * SEQ + q_tok) * DIM + (size_t)H * HD + quad * 4;
#pragma unroll
  for (int mg2 = 0; mg2 < 8; ++mg2)
    *(f32x4*)(op + mg2 * 16) = o_acc[mg2];
  if (lane < 16) {
    size_t mloff = (((size_t)c * SEQ + q_tok) * NH + H) * 2;
    ml[mloff] = m_i;
    ml[mloff + 1] = l_i;
  }
}

// ---------------------------------------------------------------------------
// 6) merge (<=3 split-key partials per (token, head)) + per-token int8 quant.
//    One block per token. Partial layout: Op[c][t][2560] f32, chunk stride
//    SEQ*DIM; ml[c][t][h][2] f32. nc(t) = ((t|31)>>6)/6 + 1 in {1..3}.
// ---------------------------------------------------------------------------
__global__ __launch_bounds__(256) void merge_quant(
    const float* __restrict__ Op, const float* __restrict__ ml,
    bf16* __restrict__ act, float* __restrict__ rs) {
  const int t = blockIdx.x;
  const int tid = threadIdx.x;
  const int nc = (((t | 31) >> 6) / 6) + 1;   // chunks covering this token: 1..3
  __shared__ float sw[3][NH];
  __shared__ float red[4];
  __shared__ float s_bc;
  if (tid < NH) {
    const size_t base = ((size_t)t * NH + tid) * 2;
    const size_t cs = (size_t)SEQ * NH * 2;
    float m0 = ml[base], l0 = ml[base + 1];
    float m1 = 0.f, l1 = 0.f, m2 = 0.f, l2 = 0.f;
    float M = m0;
    if (nc > 1) { m1 = ml[base + cs];     l1 = ml[base + cs + 1];     M = fmaxf(M, m1); }
    if (nc > 2) { m2 = ml[base + 2 * cs]; l2 = ml[base + 2 * cs + 1]; M = fmaxf(M, m2); }
    float w0 = __expf(m0 - M), w1 = 0.f, w2 = 0.f;
    float L = w0 * l0;
    if (nc > 1) { w1 = __expf(m1 - M); L += w1 * l1; }
    if (nc > 2) { w2 = __expf(m2 - M); L += w2 * l2; }
    const float invL = 1.f / L;
    sw[0][tid] = w0 * invL;
    sw[1][tid] = w1 * invL;
    sw[2][tid] = w2 * invL;
  }
  __syncthreads();
  float vals[10];
  float amax = 0.f;
  const float* ob = Op + (size_t)t * DIM;
  const size_t cs = (size_t)SEQ * DIM;
#pragma unroll
  for (int j = 0; j < 10; ++j) {
    int d = j * 256 + tid;
    int h = d >> 7;
    float v = ob[d] * sw[0][h];
    if (nc > 1) v += ob[d + cs] * sw[1][h];
    if (nc > 2) v += ob[d + 2 * cs] * sw[2][h];
    vals[j] = v;
    amax = fmaxf(amax, fabsf(v));
  }
  for (int off = 32; off; off >>= 1) amax = fmaxf(amax, __shfl_xor(amax, off));
  if ((tid & 63) == 0) red[tid >> 6] = amax;
  __syncthreads();
  if (tid == 0) {
    float mm = fmaxf(fmaxf(red[0], red[1]), fmaxf(red[2], red[3]));
    mm = fmaxf(mm, 1e-5f);
    s_bc = 127.f / mm;
    rs[t] = mm / 127.f;
  }
  __syncthreads();
  const float s = s_bc;
  bf16* ar = act + (size_t)t * DIM;
#pragma unroll
  for (int j = 0; j < 10; ++j) {
    float q = rintf(vals[j] * s);
    q = fminf(fmaxf(q, -128.f), 127.f);
    ar[j * 256 + tid] = (bf16)q;
  }
}

// ---------------------------------------------------------------------------
extern "C" void kernel_launch(void* const* d_in, const int* in_sizes, int n_in,
                              void* d_out, int out_size, void* d_ws, size_t ws_size,
                              hipStream_t stream) {
  const float* x      = (const float*)d_in[0];
  const float* w_qkv  = (const float*)d_in[1];
  const float* ws_qkv = (const float*)d_in[2];
  const float* w_o    = (const float*)d_in[3];
  const float* ws_o   = (const float*)d_in[4];
  const float* qnw    = (const float*)d_in[5];
  const float* knw    = (const float*)d_in[6];
  float* out = (float*)d_out;

  // Workspace is 256 MiB; ~130 MB used, no aliasing needed.
  char* p = (char*)d_ws;
  bf16*  act1 = (bf16*)p;  p += (size_t)SEQ * DIM * 2;
  float* rs1  = (float*)p; p += 4096;
  bf16*  wqdq = (bf16*)p;  p += (size_t)QKV_OUT * DIM * 2;
  bf16*  wodq = (bf16*)p;  p += (size_t)DIM * DIM * 2;
  float* qkvA = (float*)p; p += (size_t)SEQ * QKV_OUT * 4;
  float* qkvB = (float*)p; p += (size_t)SEQ * QKV_OUT * 4;
  bf16*  Qb   = (bf16*)p;  p += (size_t)SEQ * NH * HD * 2;
  bf16*  Kb   = (bf16*)p;  p += (size_t)NKV * SEQ * HD * 2;
  bf16*  Vt   = (bf16*)p;  p += (size_t)NKV * HD * SEQ * 2;
  bf16*  act2 = (bf16*)p;  p += (size_t)SEQ * DIM * 2;
  float* rs2  = (float*)p; p += 4096;
  float* rope = (float*)p; p += (size_t)SEQ * 64 * 2 * 4;       // 512 KB
  float* Opart = (float*)p; p += (size_t)3 * SEQ * DIM * 4;     // 31.5 MB
  float* mlbuf = (float*)p; p += (size_t)3 * SEQ * NH * 2 * 4;  // 492 KB

  {
    long n1_4 = (long)QKV_OUT * DIM / 4;                 // 2,457,600 (= 9600*256)
    int dq_blocks = (int)((n1_4 + 255) / 256);           // 9600
    int rope_blocks = (SEQ * 64 + 255) / 256;            // 256
    fused_pre<<<SEQ + dq_blocks + rope_blocks, 256, 0, stream>>>(
        x, act1, rs1, w_qkv, ws_qkv, wqdq, rope, n1_4);
  }
  // GEMM1: BM=128, BN=128, split-K x2. Grid 480 1-D: m = b/60, n = (b%60)%30,
  // z = (b%60)/30.
  gemm_pipe<128, 128><<<480, 256, 0, stream>>>(
      act1, wqdq, rs1, qkvA, QKV_OUT, DIM, DIM / 2, (size_t)SEQ * QKV_OUT, 60, 30);
  // fused qk rmsnorm+rope (6400 blocks) + V transpose (80 blocks)
  fused_post<<<6480, 256, 0, stream>>>(qkvA, qkvB, qnw, knw, rope, Qb, Kb, Vt);
  // split-key attention (600 blocks) + w_o dequant overlap (1600 blocks)
  attn_mfma<<<2200, 256, 0, stream>>>(Qb, Kb, Vt, Opart, mlbuf, w_o, ws_o, wodq);
  // merge partials + per-token quant
  merge_quant<<<SEQ, 256, 0, stream>>>(Opart, mlbuf, act2, rs2);
  // GEMM2: BM=64, BN=64, full K. Grid 640 1-D: m = b/40, n = b%40.
  gemm_pipe<64, 64><<<640, 256, 0, stream>>>(
      act2, wodq, rs2, out, DIM, DIM, DIM, 0, 40, 40);
}